// Round 2
// baseline (184.493 us; speedup 1.0000x reference)
//
#include <hip/hip_runtime.h>

#define KD 1536
#define ND 3072
#define MD 784
#define TT 16

typedef __attribute__((ext_vector_type(8))) short short8;
typedef __attribute__((ext_vector_type(4))) float floatx4;

__device__ __forceinline__ unsigned short f2bf(float f) {
    unsigned int x = __float_as_uint(f);
    unsigned int r = (x + 0x7fffu + ((x >> 16) & 1u)) >> 16;
    return (unsigned short)r;
}

__device__ __forceinline__ void gld_lds16(const unsigned short* g, unsigned short* l) {
    __builtin_amdgcn_global_load_lds((const __attribute__((address_space(1))) void*)g,
                                     (__attribute__((address_space(3))) void*)l, 16, 0, 0);
}

// =============== prep: ROI (all 768 blocks) + packA (0..383) / packB (384..767) ===============
__global__ __launch_bounds__(256) void prep_k(const float* __restrict__ y,
                                              const float* __restrict__ x_t,
                                              const float* __restrict__ rois,
                                              const float* __restrict__ conv_w,
                                              unsigned short* __restrict__ Ap,
                                              unsigned short* __restrict__ Bp,
                                              float* __restrict__ mr) {
    __shared__ float sm[64 * 197];
    __shared__ float wx0s[14], wx1s[14], wy0s[14], wy1s[14];
    __shared__ int x0s[14], x1s[14], y0s[14], y1s[14], vxs[14], vys[14];
    const int bid = blockIdx.x;
    const int tid = threadIdx.x;

    // ---- ROI align for (t, o-chunk): x_t -> mr[m][ND], m = t*49 + ij
    const int t = bid / 48;
    const int o0 = (bid % 48) * 64;

    if (tid < 14) {
        float b0 = rois[t * 4 + 0] * 0.0625f, b1 = rois[t * 4 + 1] * 0.0625f;
        float b2 = rois[t * 4 + 2] * 0.0625f, b3 = rois[t * 4 + 3] * 0.0625f;
        float rw = fmaxf(b2 - b0, 1.0f), rh = fmaxf(b3 - b1, 1.0f);
        float bw = rw * (1.0f / 7.0f), bh = rh * (1.0f / 7.0f);
        int p = tid;
        float pos = (float)(p >> 1) + 0.25f + 0.5f * (float)(p & 1);
        float xs = b0 + pos * bw;
        float ysv = b1 + pos * bh;
        vxs[p] = (xs >= -1.0f && xs <= 14.0f);
        vys[p] = (ysv >= -1.0f && ysv <= 14.0f);
        float xc = fminf(fmaxf(xs, 0.0f), 13.0f);
        float yc = fminf(fmaxf(ysv, 0.0f), 13.0f);
        int x0 = (int)floorf(xc), y0 = (int)floorf(yc);
        x0s[p] = x0; y0s[p] = y0;
        x1s[p] = min(x0 + 1, 13); y1s[p] = min(y0 + 1, 13);
        float lx = xc - (float)x0, ly = yc - (float)y0;
        wx0s[p] = 1.0f - lx; wx1s[p] = lx; wy0s[p] = 1.0f - ly; wy1s[p] = ly;
    }
    for (int f = tid; f < 64 * 196; f += 256) {
        int c = f / 196, pix = f % 196;
        sm[c * 197 + pix] = x_t[(size_t)(o0 + c) * 3136 + t * 196 + pix];
    }
    __syncthreads();
    for (int item = tid; item < 64 * 49; item += 256) {
        int c = item & 63, ij = item >> 6;
        int i = ij / 7, j = ij % 7;
        const float* base = &sm[c * 197];
        float sum = 0.0f;
#pragma unroll
        for (int s = 0; s < 2; ++s) {
            int p = 2 * i + s;
#pragma unroll
            for (int u = 0; u < 2; ++u) {
                int q = 2 * j + u;
                if (vys[p] && vxs[q]) {
                    float v00 = base[y0s[p] * 14 + x0s[q]];
                    float v01 = base[y0s[p] * 14 + x1s[q]];
                    float v10 = base[y1s[p] * 14 + x0s[q]];
                    float v11 = base[y1s[p] * 14 + x1s[q]];
                    sum += wy0s[p] * (wx0s[q] * v00 + wx1s[q] * v01) +
                           wy1s[p] * (wx0s[q] * v10 + wx1s[q] * v11);
                }
            }
        }
        mr[(size_t)(t * 49 + ij) * ND + o0 + c] = 0.25f * sum;
    }

    if (bid < 384) {
        // ---- packA: block = (t2, kc). Coalesced frame read into LDS, scatter even pixels.
        __syncthreads();
        int t2 = bid / 24, kc = bid % 24;
        for (int f = tid; f < 64 * 196; f += 256) {
            int c = f / 196, pix = f % 196;
            sm[c * 197 + pix] = y[(size_t)(kc * 64 + c) * 3136 + t2 * 196 + pix];
        }
        __syncthreads();
        for (int item = tid; item < 64 * 49; item += 256) {
            int c = item & 63, ij = item >> 6;
            int i = ij / 7, j = ij % 7;
            Ap[(size_t)(t2 * 49 + ij) * KD + kc * 64 + c] =
                f2bf(sm[c * 197 + (2 * i) * 14 + 2 * j]);
        }
    } else {
        // ---- packB: conv_w fp32 [o][c] -> bf16 [ND][KD], fully coalesced
        size_t base = (size_t)(bid - 384) * 12288;
#pragma unroll
        for (int v = 0; v < 12; ++v) {
            size_t e = base + v * 1024 + tid * 4;
            float4 w4 = *(const float4*)(conv_w + e);
            ushort4 o;
            o.x = f2bf(w4.x); o.y = f2bf(w4.y); o.z = f2bf(w4.z); o.w = f2bf(w4.w);
            *(ushort4*)(Bp + e) = o;
        }
        // no zerofill: gemm discards rows >= MD (poison there is benign)
    }
}

// =============== fused gemm: block = (128-ch chunk, t). 64x128 tile (49 valid rows),
// BK=64, global_load_lds(16B) dbuf, XOR-chunk-swizzled LDS (2-way max, free).
// Staging passes a WAVE-UNIFORM LDS base (hardware adds lane*16B); all per-lane
// variation (row, swizzled chunk L) is in the global source address (m97/m173 idiom).
// Epilogue: BN + exact GELU + *mr -> W tile in reused LDS -> coalesced scatter + x_t add -> out.
// Rows 49..63 of the A tile are neighboring-t / poison data; their outputs are discarded
// (each MFMA output row depends only on its own A row, so no contamination).
__global__ __launch_bounds__(256, 2) void gemm_k(const unsigned short* __restrict__ Ap,
                                                 const unsigned short* __restrict__ Bp,
                                                 const float* __restrict__ cb,
                                                 const float* __restrict__ gm,
                                                 const float* __restrict__ bt,
                                                 const float* __restrict__ rm,
                                                 const float* __restrict__ rv,
                                                 const float* __restrict__ mr,
                                                 const float* __restrict__ x_t,
                                                 const float* __restrict__ rois,
                                                 float* __restrict__ out) {
    __shared__ unsigned short smem[24576];   // 48 KB: As dbuf (2x8KB) + Bs dbuf (2x16KB); reused as Wl f32[49][132]
    unsigned short* const As0 = smem;
    unsigned short* const As1 = smem + 4096;
    unsigned short* const Bs0 = smem + 8192;
    unsigned short* const Bs1 = smem + 16384;

    const int tid = threadIdx.x;
    const int n0 = blockIdx.x * 128;
    const int t = blockIdx.y;
    const int aRow0 = t * 49;
    const int wv = tid >> 6;
    const int lane = tid & 63;
    const int wm = wv >> 1, wn = wv & 1;          // wave tile: 32 rows x 64 cols
    const int l15 = lane & 15, quad = lane >> 4;

    floatx4 acc[2][4] = {};

    // A tile: 64 rows x 64 ushorts = 512 16B-chunks; wave w stages chunks [w*128, w*128+128).
    // B tile: 128 rows x 64 ushorts = 1024 chunks; wave w stages [w*256, w*256+256).
    // chunk idx -> row = idx>>3, phys chunk pch = idx&7; global fetches logical L = pch ^ (row&7).
    auto stage = [&](unsigned short* aDst, unsigned short* bDst, int kt) {
#pragma unroll
        for (int v = 0; v < 2; ++v) {
            int idx = wv * 128 + v * 64 + lane;
            int row = idx >> 3, pch = idx & 7;
            int L = pch ^ (row & 7);
            gld_lds16(Ap + (size_t)(aRow0 + row) * KD + kt + L * 8,
                      aDst + (wv * 128 + v * 64) * 8);
        }
#pragma unroll
        for (int v = 0; v < 4; ++v) {
            int idx = wv * 256 + v * 64 + lane;
            int row = idx >> 3, pch = idx & 7;
            int L = pch ^ (row & 7);
            gld_lds16(Bp + (size_t)(n0 + row) * KD + kt + L * 8,
                      bDst + (wv * 256 + v * 64) * 8);
        }
    };

    stage(As0, Bs0, 0);
    int p = 0;
    for (int kt = 0; kt < KD; kt += 64, p ^= 1) {
        __syncthreads();   // drains DMA into buf p; also orders vs prior reads of buf p^1
        if (kt + 64 < KD)
            stage(p ? As0 : As1, p ? Bs0 : Bs1, kt + 64);
        const unsigned short* Ab = p ? As1 : As0;
        const unsigned short* Bb = p ? Bs1 : Bs0;
#pragma unroll
        for (int ko = 0; ko < 2; ++ko) {
            const int ch = ((ko * 4 + quad) ^ (l15 & 7)) * 8;  // phys chunk offset (ushorts)
            short8 a0 = *(const short8*)(Ab + (wm * 32 + l15) * 64 + ch);
            short8 a1 = *(const short8*)(Ab + (wm * 32 + 16 + l15) * 64 + ch);
#pragma unroll
            for (int ni = 0; ni < 4; ++ni) {
                short8 bn = *(const short8*)(Bb + (wn * 64 + ni * 16 + l15) * 64 + ch);
                acc[0][ni] = __builtin_amdgcn_mfma_f32_16x16x32_bf16(a0, bn, acc[0][ni], 0, 0, 0);
                acc[1][ni] = __builtin_amdgcn_mfma_f32_16x16x32_bf16(a1, bn, acc[1][ni], 0, 0, 0);
            }
        }
    }

    // ---- epilogue: BN + exact GELU, multiply mr, stage W tile in LDS (pitch 132: no conflicts)
    __syncthreads();                 // all waves done reading As/Bs before reuse
    float* Wl = (float*)smem;        // [49][132] = 25.9 KB <= 48 KB
#pragma unroll
    for (int ni = 0; ni < 4; ++ni) {
        int cl = wn * 64 + ni * 16 + l15;    // local col 0..127
        int n = n0 + cl;
        float scale = gm[n] / sqrtf(rv[n] + 1e-6f);
        float shift = (cb[n] - rm[n]) * scale + bt[n];
#pragma unroll
        for (int mi = 0; mi < 2; ++mi) {
#pragma unroll
            for (int r = 0; r < 4; ++r) {
                int m = wm * 32 + mi * 16 + quad * 4 + r;
                if (m < 49) {
                    float v = acc[mi][ni][r] * scale + shift;
                    float g = 0.5f * v * (1.0f + erff(v * 0.70710678118654752f));
                    Wl[m * 132 + cl] = g * mr[(size_t)(aRow0 + m) * ND + n];
                }
            }
        }
    }
    __syncthreads();

    // ---- scatter + residual add: out = x_t + place(W) for this (t, 128-ch chunk)
    float b0 = rois[t * 4 + 0] * 0.0625f, b1 = rois[t * 4 + 1] * 0.0625f;
    float b2 = rois[t * 4 + 2] * 0.0625f, b3 = rois[t * 4 + 3] * 0.0625f;
    int sxi = (int)floorf(b0), syi = (int)floorf(b1);
    int exi = (int)ceilf(b2), eyi = (int)ceilf(b3);
    int ml = (sxi + 7 < 14) ? sxi : exi - 7;
    int mt = (syi + 7 < 14) ? syi : eyi - 7;
    ml = min(max(ml, 0), 7);
    mt = min(max(mt, 0), 7);

    for (int i4 = tid; i4 < 128 * 49; i4 += 256) {
        int c = i4 / 49, p4 = i4 % 49;
        size_t e0 = (size_t)(n0 + c) * 3136 + t * 196 + p4 * 4;
        float4 xv = *(const float4*)(x_t + e0);
        float r4[4] = {xv.x, xv.y, xv.z, xv.w};
#pragma unroll
        for (int u = 0; u < 4; ++u) {
            int pix = p4 * 4 + u;
            int h = pix / 14, w = pix % 14;
            int i = h - mt, j = w - ml;
            if (i >= 0 && i < 7 && j >= 0 && j < 7)
                r4[u] += Wl[(i * 7 + j) * 132 + c];
        }
        *(float4*)(out + e0) = make_float4(r4[0], r4[1], r4[2], r4[3]);
    }
}

extern "C" void kernel_launch(void* const* d_in, const int* in_sizes, int n_in,
                              void* d_out, int out_size, void* d_ws, size_t ws_size,
                              hipStream_t stream) {
    const float* y = (const float*)d_in[0];
    const float* x_t = (const float*)d_in[1];
    const float* rois = (const float*)d_in[2];
    const float* conv_w = (const float*)d_in[3];
    const float* cb = (const float*)d_in[4];
    const float* gm = (const float*)d_in[5];
    const float* bt = (const float*)d_in[6];
    const float* rm = (const float*)d_in[7];
    const float* rv = (const float*)d_in[8];
    float* out = (float*)d_out;

    char* ws = (char*)d_ws;
    unsigned short* Ap = (unsigned short*)ws;                 // 832*1536*2 B (rows >= 784 poison: staged for t=15 tile tail, outputs discarded)
    unsigned short* Bp = (unsigned short*)(ws + 2555904);     // 3072*1536*2 = 9,437,184 B
    float* mr = (float*)(ws + 2555904 + 9437184);             // 784*3072*4 = 9,633,792 B

    prep_k<<<768, 256, 0, stream>>>(y, x_t, rois, conv_w, Ap, Bp, mr);
    gemm_k<<<dim3(ND / 128, TT), 256, 0, stream>>>(Ap, Bp, cb, gm, bt, rm, rv, mr, x_t, rois, out);
}

// Round 3
// 170.064 us; speedup vs baseline: 1.0848x; 1.0848x over previous
//
#include <hip/hip_runtime.h>

#define KD 1536
#define ND 3072
#define MD 784
#define TT 16

typedef __attribute__((ext_vector_type(8))) short short8;
typedef __attribute__((ext_vector_type(4))) float floatx4;

__device__ __forceinline__ unsigned short f2bf(float f) {
    unsigned int x = __float_as_uint(f);
    unsigned int r = (x + 0x7fffu + ((x >> 16) & 1u)) >> 16;
    return (unsigned short)r;
}

__device__ __forceinline__ void gld_lds16(const unsigned short* g, unsigned short* l) {
    __builtin_amdgcn_global_load_lds((const __attribute__((address_space(1))) void*)g,
                                     (__attribute__((address_space(3))) void*)l, 16, 0, 0);
}

// =============== prep: ROI (all 768 blocks) + packA (0..383) / packB (384..767) ===============
__global__ __launch_bounds__(256) void prep_k(const float* __restrict__ y,
                                              const float* __restrict__ x_t,
                                              const float* __restrict__ rois,
                                              const float* __restrict__ conv_w,
                                              unsigned short* __restrict__ Ap,
                                              unsigned short* __restrict__ Bp,
                                              float* __restrict__ mr) {
    __shared__ float sm[64 * 197];
    __shared__ float wx0s[14], wx1s[14], wy0s[14], wy1s[14];
    __shared__ int x0s[14], x1s[14], y0s[14], y1s[14], vxs[14], vys[14];
    const int bid = blockIdx.x;
    const int tid = threadIdx.x;

    // ---- ROI align for (t, o-chunk): x_t -> mr[m][ND], m = t*49 + ij
    const int t = bid / 48;
    const int o0 = (bid % 48) * 64;

    if (tid < 14) {
        float b0 = rois[t * 4 + 0] * 0.0625f, b1 = rois[t * 4 + 1] * 0.0625f;
        float b2 = rois[t * 4 + 2] * 0.0625f, b3 = rois[t * 4 + 3] * 0.0625f;
        float rw = fmaxf(b2 - b0, 1.0f), rh = fmaxf(b3 - b1, 1.0f);
        float bw = rw * (1.0f / 7.0f), bh = rh * (1.0f / 7.0f);
        int p = tid;
        float pos = (float)(p >> 1) + 0.25f + 0.5f * (float)(p & 1);
        float xs = b0 + pos * bw;
        float ysv = b1 + pos * bh;
        vxs[p] = (xs >= -1.0f && xs <= 14.0f);
        vys[p] = (ysv >= -1.0f && ysv <= 14.0f);
        float xc = fminf(fmaxf(xs, 0.0f), 13.0f);
        float yc = fminf(fmaxf(ysv, 0.0f), 13.0f);
        int x0 = (int)floorf(xc), y0 = (int)floorf(yc);
        x0s[p] = x0; y0s[p] = y0;
        x1s[p] = min(x0 + 1, 13); y1s[p] = min(y0 + 1, 13);
        float lx = xc - (float)x0, ly = yc - (float)y0;
        wx0s[p] = 1.0f - lx; wx1s[p] = lx; wy0s[p] = 1.0f - ly; wy1s[p] = ly;
    }
    for (int f = tid; f < 64 * 196; f += 256) {
        int c = f / 196, pix = f % 196;
        sm[c * 197 + pix] = x_t[(size_t)(o0 + c) * 3136 + t * 196 + pix];
    }
    __syncthreads();
    for (int item = tid; item < 64 * 49; item += 256) {
        int c = item & 63, ij = item >> 6;
        int i = ij / 7, j = ij % 7;
        const float* base = &sm[c * 197];
        float sum = 0.0f;
#pragma unroll
        for (int s = 0; s < 2; ++s) {
            int p = 2 * i + s;
#pragma unroll
            for (int u = 0; u < 2; ++u) {
                int q = 2 * j + u;
                if (vys[p] && vxs[q]) {
                    float v00 = base[y0s[p] * 14 + x0s[q]];
                    float v01 = base[y0s[p] * 14 + x1s[q]];
                    float v10 = base[y1s[p] * 14 + x0s[q]];
                    float v11 = base[y1s[p] * 14 + x1s[q]];
                    sum += wy0s[p] * (wx0s[q] * v00 + wx1s[q] * v01) +
                           wy1s[p] * (wx0s[q] * v10 + wx1s[q] * v11);
                }
            }
        }
        mr[(size_t)(t * 49 + ij) * ND + o0 + c] = 0.25f * sum;
    }

    if (bid < 384) {
        // ---- packA: block = (t2, kc). Coalesced frame read into LDS, scatter even pixels.
        __syncthreads();
        int t2 = bid / 24, kc = bid % 24;
        for (int f = tid; f < 64 * 196; f += 256) {
            int c = f / 196, pix = f % 196;
            sm[c * 197 + pix] = y[(size_t)(kc * 64 + c) * 3136 + t2 * 196 + pix];
        }
        __syncthreads();
        for (int item = tid; item < 64 * 49; item += 256) {
            int c = item & 63, ij = item >> 6;
            int i = ij / 7, j = ij % 7;
            Ap[(size_t)(t2 * 49 + ij) * KD + kc * 64 + c] =
                f2bf(sm[c * 197 + (2 * i) * 14 + 2 * j]);
        }
    } else {
        // ---- packB: conv_w fp32 [o][c] -> bf16 [ND][KD], fully coalesced
        size_t base = (size_t)(bid - 384) * 12288;
#pragma unroll
        for (int v = 0; v < 12; ++v) {
            size_t e = base + v * 1024 + tid * 4;
            float4 w4 = *(const float4*)(conv_w + e);
            ushort4 o;
            o.x = f2bf(w4.x); o.y = f2bf(w4.y); o.z = f2bf(w4.z); o.w = f2bf(w4.w);
            *(ushort4*)(Bp + e) = o;
        }
        // no zerofill: gemm discards rows >= MD (poison there is benign)
    }
}

// =============== fused gemm: block = (64-ch chunk, t). 64x64 tile (49 valid rows), BK=64,
// global_load_lds(16B) dbuf, XOR-chunk swizzle (2-way max, free), 1 barrier/iter.
// Geometry = round-0 proven structure: 32 KB LDS, 4 blocks/CU, 768 blocks (3/CU resident).
// Epilogue fused: BN + exact GELU + *mr -> W tile in reused LDS -> scatter + x_t add -> out.
// Rows 49..63 of the A tile are neighboring-t / poison rows; their outputs are discarded
// (each MFMA output row depends only on its own A row -> no contamination).
__global__ __launch_bounds__(256, 4) void gemm_k(const unsigned short* __restrict__ Ap,
                                                 const unsigned short* __restrict__ Bp,
                                                 const float* __restrict__ cb,
                                                 const float* __restrict__ gm,
                                                 const float* __restrict__ bt,
                                                 const float* __restrict__ rm,
                                                 const float* __restrict__ rv,
                                                 const float* __restrict__ mr,
                                                 const float* __restrict__ x_t,
                                                 const float* __restrict__ rois,
                                                 float* __restrict__ out) {
    __shared__ unsigned short smem[16384];   // 32 KB: As dbuf 2x8KB + Bs dbuf 2x8KB; reused as Wl f32[49][65]
    unsigned short* const As0 = smem;
    unsigned short* const As1 = smem + 4096;
    unsigned short* const Bs0 = smem + 8192;
    unsigned short* const Bs1 = smem + 12288;

    const int tid = threadIdx.x;
    const int n0 = blockIdx.x * 64;
    const int t = blockIdx.y;
    const int aRow0 = t * 49;
    const int wv = tid >> 6;
    const int lane = tid & 63;
    const int wm = wv >> 1, wn = wv & 1;
    const int l15 = lane & 15, quad = lane >> 4;
    const int prow = lane >> 3, pch = lane & 7;
    const int L = pch ^ (prow & 7);

    // staging: wv0 -> A rows 0..31, wv1 -> A rows 32..63, wv2 -> B rows 0..31, wv3 -> B rows 32..63
    // LDS dest is wave-uniform (+ hardware lane*16B); swizzle carried in the global source addr.
    const unsigned short* gbase;
    unsigned short *lb0, *lb1;
    if (wv < 2) {
        gbase = Ap + (size_t)(aRow0 + wv * 32 + prow) * KD + L * 8;
        lb0 = &As0[(wv * 32) * 64];
        lb1 = &As1[(wv * 32) * 64];
    } else {
        gbase = Bp + (size_t)(n0 + (wv - 2) * 32 + prow) * KD + L * 8;
        lb0 = &Bs0[((wv - 2) * 32) * 64];
        lb1 = &Bs1[((wv - 2) * 32) * 64];
    }

    floatx4 acc00 = {0.f, 0.f, 0.f, 0.f}, acc01 = {0.f, 0.f, 0.f, 0.f};
    floatx4 acc10 = {0.f, 0.f, 0.f, 0.f}, acc11 = {0.f, 0.f, 0.f, 0.f};

    // preload tile 0 into buffer 0
#pragma unroll
    for (int j = 0; j < 4; ++j)
        gld_lds16(gbase + (size_t)j * 8 * KD, lb0 + j * 512);

    int p = 0;
    for (int kt = 0; kt < KD; kt += 64, p ^= 1) {
        __syncthreads();   // drains DMA into buf p; also orders vs prior reads of buf p^1
        if (kt + 64 < KD) {
            unsigned short* lb = p ? lb0 : lb1;          // next buffer = p^1
            const unsigned short* gb = gbase + kt + 64;
#pragma unroll
            for (int j = 0; j < 4; ++j)
                gld_lds16(gb + (size_t)j * 8 * KD, lb + j * 512);
        }
        const unsigned short* Ab = p ? As1 : As0;
        const unsigned short* Bb = p ? Bs1 : Bs0;
#pragma unroll
        for (int ko = 0; ko < 2; ++ko) {
            int ch = ((ko * 4 + quad) ^ (l15 & 7)) * 8;  // phys chunk offset (ushorts)
            short8 a0 = *(const short8*)(Ab + (wm * 32 + l15) * 64 + ch);
            short8 a1 = *(const short8*)(Ab + (wm * 32 + 16 + l15) * 64 + ch);
            short8 b0 = *(const short8*)(Bb + (wn * 32 + l15) * 64 + ch);
            short8 b1 = *(const short8*)(Bb + (wn * 32 + 16 + l15) * 64 + ch);
            acc00 = __builtin_amdgcn_mfma_f32_16x16x32_bf16(a0, b0, acc00, 0, 0, 0);
            acc01 = __builtin_amdgcn_mfma_f32_16x16x32_bf16(a0, b1, acc01, 0, 0, 0);
            acc10 = __builtin_amdgcn_mfma_f32_16x16x32_bf16(a1, b0, acc10, 0, 0, 0);
            acc11 = __builtin_amdgcn_mfma_f32_16x16x32_bf16(a1, b1, acc11, 0, 0, 0);
        }
    }

    // ---- epilogue: BN + exact GELU, multiply mr, stage W tile in reused LDS (pitch 65)
    __syncthreads();                 // all waves done reading As/Bs before reuse
    float* Wl = (float*)smem;        // [49][65] = 12.7 KB <= 32 KB
#pragma unroll
    for (int ni = 0; ni < 2; ++ni) {
        int cl = wn * 32 + ni * 16 + l15;    // local col 0..63
        int n = n0 + cl;
        float scale = gm[n] / sqrtf(rv[n] + 1e-6f);
        float shift = (cb[n] - rm[n]) * scale + bt[n];
#pragma unroll
        for (int mi = 0; mi < 2; ++mi) {
            floatx4 a = (ni == 0) ? (mi == 0 ? acc00 : acc10) : (mi == 0 ? acc01 : acc11);
#pragma unroll
            for (int r = 0; r < 4; ++r) {
                int m = wm * 32 + mi * 16 + quad * 4 + r;
                if (m < 49) {
                    float v = a[r] * scale + shift;
                    float g = 0.5f * v * (1.0f + erff(v * 0.70710678118654752f));
                    Wl[m * 65 + cl] = g * mr[(size_t)(aRow0 + m) * ND + n];
                }
            }
        }
    }
    __syncthreads();

    // ---- scatter + residual add: out = x_t + place(W) for this (t, 64-ch chunk)
    float b0 = rois[t * 4 + 0] * 0.0625f, b1 = rois[t * 4 + 1] * 0.0625f;
    float b2 = rois[t * 4 + 2] * 0.0625f, b3 = rois[t * 4 + 3] * 0.0625f;
    int sxi = (int)floorf(b0), syi = (int)floorf(b1);
    int exi = (int)ceilf(b2), eyi = (int)ceilf(b3);
    int ml = (sxi + 7 < 14) ? sxi : exi - 7;
    int mt = (syi + 7 < 14) ? syi : eyi - 7;
    ml = min(max(ml, 0), 7);
    mt = min(max(mt, 0), 7);

    for (int i4 = tid; i4 < 64 * 49; i4 += 256) {
        int c = i4 / 49, p4 = i4 % 49;
        size_t e0 = (size_t)(n0 + c) * 3136 + t * 196 + p4 * 4;
        float4 xv = *(const float4*)(x_t + e0);
        float r4[4] = {xv.x, xv.y, xv.z, xv.w};
#pragma unroll
        for (int u = 0; u < 4; ++u) {
            int pix = p4 * 4 + u;
            int h = pix / 14, w = pix % 14;
            int i = h - mt, j = w - ml;
            if (i >= 0 && i < 7 && j >= 0 && j < 7)
                r4[u] += Wl[(i * 7 + j) * 65 + c];
        }
        *(float4*)(out + e0) = make_float4(r4[0], r4[1], r4[2], r4[3]);
    }
}

extern "C" void kernel_launch(void* const* d_in, const int* in_sizes, int n_in,
                              void* d_out, int out_size, void* d_ws, size_t ws_size,
                              hipStream_t stream) {
    const float* y = (const float*)d_in[0];
    const float* x_t = (const float*)d_in[1];
    const float* rois = (const float*)d_in[2];
    const float* conv_w = (const float*)d_in[3];
    const float* cb = (const float*)d_in[4];
    const float* gm = (const float*)d_in[5];
    const float* bt = (const float*)d_in[6];
    const float* rm = (const float*)d_in[7];
    const float* rv = (const float*)d_in[8];
    float* out = (float*)d_out;

    char* ws = (char*)d_ws;
    unsigned short* Ap = (unsigned short*)ws;                 // 832*1536*2 B (rows >= 784 poison: staged for t=15 tile tail, outputs discarded)
    unsigned short* Bp = (unsigned short*)(ws + 2555904);     // 3072*1536*2 = 9,437,184 B
    float* mr = (float*)(ws + 2555904 + 9437184);             // 784*3072*4 = 9,633,792 B

    prep_k<<<768, 256, 0, stream>>>(y, x_t, rois, conv_w, Ap, Bp, mr);
    gemm_k<<<dim3(ND / 64, TT), 256, 0, stream>>>(Ap, Bp, cb, gm, bt, rm, rv, mr, x_t, rois, out);
}

// Round 5
// 165.429 us; speedup vs baseline: 1.1152x; 1.0280x over previous
//
#include <hip/hip_runtime.h>

#define KD 1536
#define ND 3072
#define MD 784
#define TT 16

typedef __attribute__((ext_vector_type(8))) short short8;
typedef __attribute__((ext_vector_type(4))) float floatx4;

__device__ __forceinline__ unsigned short f2bf(float f) {
    unsigned int x = __float_as_uint(f);
    unsigned int r = (x + 0x7fffu + ((x >> 16) & 1u)) >> 16;
    return (unsigned short)r;
}

__device__ __forceinline__ void gld_lds16(const unsigned short* g, unsigned short* l) {
    __builtin_amdgcn_global_load_lds((const __attribute__((address_space(1))) void*)g,
                                     (__attribute__((address_space(3))) void*)l, 16, 0, 0);
}

// =============== prep: packA (0..383) / packB (384..767). ROI moved into gemm epilogue. ===============
__global__ __launch_bounds__(256) void prep_k(const float* __restrict__ y,
                                              const float* __restrict__ conv_w,
                                              unsigned short* __restrict__ Ap,
                                              unsigned short* __restrict__ Bp) {
    __shared__ float sm[64 * 197];
    const int bid = blockIdx.x;
    const int tid = threadIdx.x;

    if (bid < 384) {
        // ---- packA: block = (t2, kc). float4 frame read into LDS, scatter even pixels as bf16.
        const int t2 = bid / 24, kc = bid % 24;
        for (int i4 = tid; i4 < 64 * 49; i4 += 256) {
            int c = i4 / 49, p4 = i4 % 49;
            float4 v = *(const float4*)(y + (size_t)(kc * 64 + c) * 3136 + t2 * 196 + p4 * 4);
            float* d = &sm[c * 197 + p4 * 4];
            d[0] = v.x; d[1] = v.y; d[2] = v.z; d[3] = v.w;
        }
        __syncthreads();
        for (int item = tid; item < 64 * 49; item += 256) {
            int c = item & 63, ij = item >> 6;
            int i = ij / 7, j = ij % 7;
            Ap[(size_t)(t2 * 49 + ij) * KD + kc * 64 + c] =
                f2bf(sm[c * 197 + (2 * i) * 14 + 2 * j]);
        }
    } else {
        // ---- packB: conv_w fp32 [o][c] -> bf16 [ND][KD], fully coalesced
        size_t base = (size_t)(bid - 384) * 12288;
#pragma unroll
        for (int v = 0; v < 12; ++v) {
            size_t e = base + v * 1024 + tid * 4;
            float4 w4 = *(const float4*)(conv_w + e);
            ushort4 o;
            o.x = f2bf(w4.x); o.y = f2bf(w4.y); o.z = f2bf(w4.z); o.w = f2bf(w4.w);
            *(ushort4*)(Bp + e) = o;
        }
        // no zerofill: gemm discards rows >= MD (poison there is benign)
    }
}

// =============== fused gemm: block = (64-ch chunk, t). 64x64 tile (49 valid rows), BK=64,
// global_load_lds(16B) dbuf, XOR-chunk swizzle, 1 barrier/iter (round-0 proven K-loop).
// Epilogue: stage x_t frame tile into LDS (aliases dead dbuf), compute ROI-align (bilinear)
// from LDS, BN + exact GELU + *mr in-register, scatter-ADD into the staged tile,
// write tile as out. mr tensor eliminated. Pitch 197: 16-lane same-pixel bilinear reads
// hit distinct banks (197 mod 32 = 5, gcd(5,32)=1).
// Rows 49..63 of the A tile are neighboring-t / poison rows; outputs discarded.
__global__ __launch_bounds__(256, 3) void gemm_k(const unsigned short* __restrict__ Ap,
                                                 const unsigned short* __restrict__ Bp,
                                                 const float* __restrict__ cb,
                                                 const float* __restrict__ gm,
                                                 const float* __restrict__ bt,
                                                 const float* __restrict__ rm,
                                                 const float* __restrict__ rv,
                                                 const float* __restrict__ x_t,
                                                 const float* __restrict__ rois,
                                                 float* __restrict__ out) {
    __shared__ float sm[64 * 197];   // 50,432 B; first 32 KB alias the K-loop double buffers
    __shared__ float wx0s[14], wx1s[14], wy0s[14], wy1s[14];
    __shared__ int x0s[14], x1s[14], y0s[14], y1s[14], vxs[14], vys[14];

    unsigned short* const smem = (unsigned short*)sm;
    unsigned short* const As0 = smem;
    unsigned short* const As1 = smem + 4096;
    unsigned short* const Bs0 = smem + 8192;
    unsigned short* const Bs1 = smem + 12288;

    const int tid = threadIdx.x;
    const int n0 = blockIdx.x * 64;
    const int t = blockIdx.y;
    const int aRow0 = t * 49;
    const int wv = tid >> 6;
    const int lane = tid & 63;
    const int wm = wv >> 1, wn = wv & 1;
    const int l15 = lane & 15, quad = lane >> 4;
    const int prow = lane >> 3, pch = lane & 7;
    const int L = pch ^ (prow & 7);

    // ROI geometry params (read only in epilogue; first K-loop barrier orders them)
    if (tid < 14) {
        float b0 = rois[t * 4 + 0] * 0.0625f, b1 = rois[t * 4 + 1] * 0.0625f;
        float b2 = rois[t * 4 + 2] * 0.0625f, b3 = rois[t * 4 + 3] * 0.0625f;
        float rw = fmaxf(b2 - b0, 1.0f), rh = fmaxf(b3 - b1, 1.0f);
        float bw = rw * (1.0f / 7.0f), bh = rh * (1.0f / 7.0f);
        int p = tid;
        float pos = (float)(p >> 1) + 0.25f + 0.5f * (float)(p & 1);
        float xs = b0 + pos * bw;
        float ysv = b1 + pos * bh;
        vxs[p] = (xs >= -1.0f && xs <= 14.0f);
        vys[p] = (ysv >= -1.0f && ysv <= 14.0f);
        float xc = fminf(fmaxf(xs, 0.0f), 13.0f);
        float yc = fminf(fmaxf(ysv, 0.0f), 13.0f);
        int x0 = (int)floorf(xc), y0 = (int)floorf(yc);
        x0s[p] = x0; y0s[p] = y0;
        x1s[p] = min(x0 + 1, 13); y1s[p] = min(y0 + 1, 13);
        float lx = xc - (float)x0, ly = yc - (float)y0;
        wx0s[p] = 1.0f - lx; wx1s[p] = lx; wy0s[p] = 1.0f - ly; wy1s[p] = ly;
    }

    // staging: wv0 -> A rows 0..31, wv1 -> A rows 32..63, wv2 -> B rows 0..31, wv3 -> B rows 32..63
    // LDS dest is wave-uniform (+ hardware lane*16B); swizzle carried in the global source addr.
    const unsigned short* gbase;
    unsigned short *lb0, *lb1;
    if (wv < 2) {
        gbase = Ap + (size_t)(aRow0 + wv * 32 + prow) * KD + L * 8;
        lb0 = &As0[(wv * 32) * 64];
        lb1 = &As1[(wv * 32) * 64];
    } else {
        gbase = Bp + (size_t)(n0 + (wv - 2) * 32 + prow) * KD + L * 8;
        lb0 = &Bs0[((wv - 2) * 32) * 64];
        lb1 = &Bs1[((wv - 2) * 32) * 64];
    }

    floatx4 acc[2][2];   // [mi][ni], static indexing only
    acc[0][0] = floatx4{0.f, 0.f, 0.f, 0.f};
    acc[0][1] = floatx4{0.f, 0.f, 0.f, 0.f};
    acc[1][0] = floatx4{0.f, 0.f, 0.f, 0.f};
    acc[1][1] = floatx4{0.f, 0.f, 0.f, 0.f};

    // preload tile 0 into buffer 0
#pragma unroll
    for (int j = 0; j < 4; ++j)
        gld_lds16(gbase + (size_t)j * 8 * KD, lb0 + j * 512);

    int p = 0;
    for (int kt = 0; kt < KD; kt += 64, p ^= 1) {
        __syncthreads();   // drains DMA into buf p; also orders vs prior reads of buf p^1
        if (kt + 64 < KD) {
            unsigned short* lb = p ? lb0 : lb1;          // next buffer = p^1
            const unsigned short* gb = gbase + kt + 64;
#pragma unroll
            for (int j = 0; j < 4; ++j)
                gld_lds16(gb + (size_t)j * 8 * KD, lb + j * 512);
        }
        const unsigned short* Ab = p ? As1 : As0;
        const unsigned short* Bb = p ? Bs1 : Bs0;
#pragma unroll
        for (int ko = 0; ko < 2; ++ko) {
            int ch = ((ko * 4 + quad) ^ (l15 & 7)) * 8;  // phys chunk offset (ushorts)
            short8 a0 = *(const short8*)(Ab + (wm * 32 + l15) * 64 + ch);
            short8 a1 = *(const short8*)(Ab + (wm * 32 + 16 + l15) * 64 + ch);
            short8 b0 = *(const short8*)(Bb + (wn * 32 + l15) * 64 + ch);
            short8 b1 = *(const short8*)(Bb + (wn * 32 + 16 + l15) * 64 + ch);
            acc[0][0] = __builtin_amdgcn_mfma_f32_16x16x32_bf16(a0, b0, acc[0][0], 0, 0, 0);
            acc[0][1] = __builtin_amdgcn_mfma_f32_16x16x32_bf16(a0, b1, acc[0][1], 0, 0, 0);
            acc[1][0] = __builtin_amdgcn_mfma_f32_16x16x32_bf16(a1, b0, acc[1][0], 0, 0, 0);
            acc[1][1] = __builtin_amdgcn_mfma_f32_16x16x32_bf16(a1, b1, acc[1][1], 0, 0, 0);
        }
    }

    // ---- epilogue phase 1: stage x_t frame tile (64ch x 196px) into sm (overwrites dbuf)
    __syncthreads();                 // all waves done with K-loop LDS
    for (int i4 = tid; i4 < 64 * 49; i4 += 256) {
        int c = i4 / 49, p4 = i4 % 49;
        float4 xv = *(const float4*)(x_t + (size_t)(n0 + c) * 3136 + t * 196 + p4 * 4);
        float* d = &sm[c * 197 + p4 * 4];
        d[0] = xv.x; d[1] = xv.y; d[2] = xv.z; d[3] = xv.w;
    }
    __syncthreads();

    // ---- phase 2: per acc element compute mr (bilinear from sm), BN + GELU, w -> acc in place
#pragma unroll
    for (int ni = 0; ni < 2; ++ni) {
        const int cl = wn * 32 + ni * 16 + l15;
        const int n = n0 + cl;
        const float scale = gm[n] / sqrtf(rv[n] + 1e-6f);
        const float shift = (cb[n] - rm[n]) * scale + bt[n];
        const float* base = &sm[cl * 197];
#pragma unroll
        for (int mi = 0; mi < 2; ++mi) {
#pragma unroll
            for (int r = 0; r < 4; ++r) {
                const int m = wm * 32 + mi * 16 + quad * 4 + r;
                if (m < 49) {
                    const int i = m / 7, j = m % 7;
                    float sum = 0.0f;
#pragma unroll
                    for (int s = 0; s < 2; ++s) {
                        int pp = 2 * i + s;
#pragma unroll
                        for (int u = 0; u < 2; ++u) {
                            int q = 2 * j + u;
                            if (vys[pp] && vxs[q]) {
                                float v00 = base[y0s[pp] * 14 + x0s[q]];
                                float v01 = base[y0s[pp] * 14 + x1s[q]];
                                float v10 = base[y1s[pp] * 14 + x0s[q]];
                                float v11 = base[y1s[pp] * 14 + x1s[q]];
                                sum += wy0s[pp] * (wx0s[q] * v00 + wx1s[q] * v01) +
                                       wy1s[pp] * (wx0s[q] * v10 + wx1s[q] * v11);
                            }
                        }
                    }
                    const float mrv = 0.25f * sum;
                    const float v = acc[mi][ni][r] * scale + shift;
                    const float g = 0.5f * v * (1.0f + erff(v * 0.70710678118654752f));
                    acc[mi][ni][r] = g * mrv;
                }
            }
        }
    }
    __syncthreads();   // all bilinear reads of sm done before scatter-adds modify it

    // ---- phase 3: scatter-ADD w into the staged tile (distinct (pixel,channel) per element)
    float b0 = rois[t * 4 + 0] * 0.0625f, b1 = rois[t * 4 + 1] * 0.0625f;
    float b2 = rois[t * 4 + 2] * 0.0625f, b3 = rois[t * 4 + 3] * 0.0625f;
    int sxi = (int)floorf(b0), syi = (int)floorf(b1);
    int exi = (int)ceilf(b2), eyi = (int)ceilf(b3);
    int ml = (sxi + 7 < 14) ? sxi : exi - 7;
    int mt = (syi + 7 < 14) ? syi : eyi - 7;
    ml = min(max(ml, 0), 7);
    mt = min(max(mt, 0), 7);

#pragma unroll
    for (int ni = 0; ni < 2; ++ni) {
        const int cl = wn * 32 + ni * 16 + l15;
#pragma unroll
        for (int mi = 0; mi < 2; ++mi) {
#pragma unroll
            for (int r = 0; r < 4; ++r) {
                const int m = wm * 32 + mi * 16 + quad * 4 + r;
                if (m < 49) {
                    const int i = m / 7, j = m % 7;
                    sm[cl * 197 + (mt + i) * 14 + (ml + j)] += acc[mi][ni][r];
                }
            }
        }
    }
    __syncthreads();

    // ---- phase 4: write tile out = x_t + scatter(W), coalesced float4
    for (int i4 = tid; i4 < 64 * 49; i4 += 256) {
        int c = i4 / 49, p4 = i4 % 49;
        const float* d = &sm[c * 197 + p4 * 4];
        size_t e0 = (size_t)(n0 + c) * 3136 + t * 196 + p4 * 4;
        *(float4*)(out + e0) = make_float4(d[0], d[1], d[2], d[3]);
    }
}

extern "C" void kernel_launch(void* const* d_in, const int* in_sizes, int n_in,
                              void* d_out, int out_size, void* d_ws, size_t ws_size,
                              hipStream_t stream) {
    const float* y = (const float*)d_in[0];
    const float* x_t = (const float*)d_in[1];
    const float* rois = (const float*)d_in[2];
    const float* conv_w = (const float*)d_in[3];
    const float* cb = (const float*)d_in[4];
    const float* gm = (const float*)d_in[5];
    const float* bt = (const float*)d_in[6];
    const float* rm = (const float*)d_in[7];
    const float* rv = (const float*)d_in[8];
    float* out = (float*)d_out;

    char* ws = (char*)d_ws;
    unsigned short* Ap = (unsigned short*)ws;                 // 832*1536*2 B (rows >= 784 poison: staged for t=15 tile tail, outputs discarded)
    unsigned short* Bp = (unsigned short*)(ws + 2555904);     // 3072*1536*2 = 9,437,184 B

    prep_k<<<768, 256, 0, stream>>>(y, conv_w, Ap, Bp);
    gemm_k<<<dim3(ND / 64, TT), 256, 0, stream>>>(Ap, Bp, cb, gm, bt, rm, rv, x_t, rois, out);
}